// Round 15
// baseline (31.434 us; speedup 1.0000x reference)
//
#include <hip/hip_runtime.h>
#include <hip/hip_bf16.h>

#define T_SEQ 1024
#define D_MODEL 256
#define VBT_W 1152   // 12 front guard + 1024 + 116 back guard

typedef __attribute__((ext_vector_type(8))) short s16x8;
typedef __attribute__((ext_vector_type(4))) float f32x4v;

__device__ __forceinline__ unsigned short f2bf(float x) {
    union { float f; unsigned int u; } v; v.f = x;
    unsigned int r = v.u + 0x7FFFu + ((v.u >> 16) & 1u);
    return (unsigned short)(r >> 16);
}

__device__ __forceinline__ s16x8 pack8(float4 a, float4 b) {
    union { s16x8 v; unsigned int u[4]; } r;
    union { __hip_bfloat162 h; unsigned int u; } t;
    t.h = __float22bfloat162_rn(make_float2(a.x, a.y)); r.u[0] = t.u;
    t.h = __float22bfloat162_rn(make_float2(a.z, a.w)); r.u[1] = t.u;
    t.h = __float22bfloat162_rn(make_float2(b.x, b.y)); r.u[2] = t.u;
    t.h = __float22bfloat162_rn(make_float2(b.z, b.w)); r.u[3] = t.u;
    return r.v;
}

// ---- cvt: x + Wq/Wk/Wv/Wo f32 -> bf16, once. 640 blocks x 256 thr, 8 elems/thr ----
__global__ __launch_bounds__(256) void cvt(
    const float* __restrict__ x,
    const float* __restrict__ Wq, const float* __restrict__ Wk,
    const float* __restrict__ Wv, const float* __restrict__ Wo,
    unsigned short* __restrict__ xb, unsigned short* __restrict__ wb)
{
    const int NX8 = (4 * T_SEQ * D_MODEL) / 8;   // 131072
    const int NW8 = (D_MODEL * D_MODEL) / 8;     // 8192
    int i8 = blockIdx.x * 256 + threadIdx.x;     // grid sized exactly: 640*256 = 163840
    if (i8 < NX8) {
        const float* p = x + (size_t)i8 * 8;
        *(s16x8*)(xb + (size_t)i8 * 8) = pack8(*(const float4*)p, *(const float4*)(p + 4));
    } else {
        int r = i8 - NX8;
        int m = r / NW8;
        int o = r - m * NW8;
        const float* W = (m == 0) ? Wq : (m == 1) ? Wk : (m == 2) ? Wv : Wo;
        const float* p = W + (size_t)o * 8;
        *(s16x8*)(wb + (size_t)m * (D_MODEL * D_MODEL) + (size_t)o * 8) =
            pack8(*(const float4*)p, *(const float4*)(p + 4));
    }
}

// ---- QKV GEMM from bf16 inputs + V-transpose + guard zeroing ----
// Same structure as R13, but staging is pure 16B copies and A-frags are direct
// short8 loads (no per-block f32 traffic, no per-block cvt).
__global__ __launch_bounds__(256) void qkv_prep(
    const unsigned short* __restrict__ xb, const unsigned short* __restrict__ wb,
    const float* __restrict__ bq, const float* __restrict__ bk, const float* __restrict__ bv,
    unsigned short* __restrict__ qb, unsigned short* __restrict__ kb,
    unsigned short* __restrict__ vbT)
{
    __shared__ unsigned short Bl[64][264];   // 528B stride (conflict-benign)

    const int tid  = threadIdx.x;
    const int lane = tid & 63;
    const int w    = tid >> 6;
    const int l15  = lane & 15, hi = lane >> 4;
    const int row0 = blockIdx.x * 64;
    const int mat  = blockIdx.y >> 2;
    const int col0 = (blockIdx.y & 3) * 64;
    const int fid  = blockIdx.y * 64 + blockIdx.x;

    const unsigned short* W = wb + (size_t)mat * (D_MODEL * D_MODEL);
    const float* bias = (mat == 0) ? bq : (mat == 1) ? bk : bv;

    // T14: prefetch A row (8 x short8 = 32 VGPR) before staging
    const int arow = row0 + w * 16 + l15;
    const unsigned short* Ap = xb + (size_t)arow * D_MODEL;
    s16x8 a8[8];
    #pragma unroll
    for (int kt = 0; kt < 8; ++kt)
        a8[kt] = *(const s16x8*)(Ap + kt * 32 + hi * 8);

    // stage W tile: pure 16B bf16 copies, coalesced
    for (int i = tid; i < 2048; i += 256) {
        int r = i >> 5, c8 = i & 31;
        *(s16x8*)&Bl[r][c8 * 8] = *(const s16x8*)(W + (size_t)(col0 + r) * D_MODEL + c8 * 8);
    }
    __syncthreads();

    f32x4v acc[4] = {};
    #pragma unroll
    for (int kt = 0; kt < 8; ++kt) {
        int koff = kt * 32 + hi * 8;
        #pragma unroll
        for (int c = 0; c < 4; ++c)
            acc[c] = __builtin_amdgcn_mfma_f32_16x16x32_bf16(a8[kt], *(const s16x8*)&Bl[c * 16 + l15][koff], acc[c], 0, 0, 0);
    }
    if (mat == 2) {
        int bq4 = row0 >> 10;
        int j0  = (row0 & 1023) + w * 16 + hi * 4;
        #pragma unroll
        for (int c = 0; c < 4; ++c) {
            int col = col0 + c * 16 + l15;
            int hh = col >> 6, dh = col & 63;
            float bs = bias[col];
            union { ushort4 u4; unsigned short s[4]; } st;
            #pragma unroll
            for (int r = 0; r < 4; ++r) st.s[r] = f2bf(acc[c][r] + bs);
            *(ushort4*)(vbT + (size_t)((bq4 * 4 + hh) * 64 + dh) * VBT_W + 12 + j0) = st.u4;
        }
    } else {
        unsigned short* o = (mat == 0) ? qb : kb;
        float sc = (mat == 0) ? 0.125f : 1.0f;
        #pragma unroll
        for (int c = 0; c < 4; ++c) {
            int col = col0 + c * 16 + l15;
            float bs = bias[col];
            #pragma unroll
            for (int r = 0; r < 4; ++r) {
                int row = row0 + w * 16 + hi * 4 + r;
                o[(size_t)row * D_MODEL + col] = f2bf((acc[c][r] + bs) * sc);
            }
        }
    }

    // side task: vbT guard-column zeroing
    int gid = fid * 256 + tid;
    if (gid < 1024 * 128) {
        int row = gid >> 7, g = gid & 127;
        int colg = (g < 12) ? g : (1024 + g);
        vbT[(size_t)row * VBT_W + colg] = 0;
    }
}

// ---- attention + O projection (R14 verbatim; wob = wb + 3*64K) ----
__global__ __launch_bounds__(512, 4) void attn_o(
    const unsigned short* __restrict__ qb, const unsigned short* __restrict__ kb,
    const unsigned short* __restrict__ vbT, const unsigned short* __restrict__ wob,
    const float* __restrict__ shift_logits, const float* __restrict__ alibi_slope,
    const float* __restrict__ bo, float* __restrict__ out)
{
    __shared__ float S[4][16][104];          // 26624 B
    __shared__ unsigned short ctxs[16][264]; //  8448 B

    const int tid  = threadIdx.x;
    const int lane = tid & 63;
    const int l15  = lane & 15, hi = lane >> 4;
    const int h    = tid >> 7;        // head team
    const int ttid = tid & 127;
    const int wl   = (tid >> 6) & 1;  // wave within team

    // XCD-aligned decode (bijective over 256 blocks): bid%8 == (t0/64)%8
    const int bid = blockIdx.x;
    const int x7  = bid & 7;
    const int i5  = bid >> 3;
    const int s_  = x7 + 8 * (i5 & 1);
    const int tl  = (i5 >> 1) & 3;
    const int b   = i5 >> 3;
    const int t0  = (s_ * 4 + tl) * 16;
    const int jbase = t0 - 12;

    const unsigned short* qrow = qb + (size_t)(b * T_SEQ + t0 + l15) * D_MODEL + h * 64;
    s16x8 aq0 = *(const s16x8*)(qrow + hi * 8);
    s16x8 aq1 = *(const s16x8*)(qrow + 32 + hi * 8);

    s16x8 bk0[3], bk1[3];
    #pragma unroll
    for (int i = 0; i < 3; ++i) {
        int cf = wl + 2 * i;
        int j = jbase + cf * 16 + l15;
        s16x8 z = {0,0,0,0,0,0,0,0};
        bk0[i] = z; bk1[i] = z;
        if (j >= 0 && j < T_SEQ) {
            const unsigned short* kr = kb + (size_t)(b * T_SEQ + j) * D_MODEL + h * 64;
            bk0[i] = *(const s16x8*)(kr + hi * 8);
            bk1[i] = *(const s16x8*)(kr + 32 + hi * 8);
        }
    }
    s16x8 bvv[2][3];
    #pragma unroll
    for (int i = 0; i < 2; ++i) {
        int c = wl * 2 + i;
        const unsigned short* vrow =
            vbT + (size_t)((b * 4 + h) * 64 + c * 16 + l15) * VBT_W + t0;
        #pragma unroll
        for (int kt = 0; kt < 3; ++kt)
            bvv[i][kt] = *(const s16x8*)(vrow + kt * 32 + hi * 8);
    }
    float l0 = shift_logits[h * 4 + 0], l1 = shift_logits[h * 4 + 1];
    float l2 = shift_logits[h * 4 + 2], l3 = shift_logits[h * 4 + 3];
    float slope = alibi_slope[h];

    #pragma unroll
    for (int i = 0; i < 3; ++i) {
        int cf = wl + 2 * i;
        f32x4v acc = {};
        acc = __builtin_amdgcn_mfma_f32_16x16x32_bf16(aq0, bk0[i], acc, 0, 0, 0);
        acc = __builtin_amdgcn_mfma_f32_16x16x32_bf16(aq1, bk1[i], acc, 0, 0, 0);
        #pragma unroll
        for (int r = 0; r < 4; ++r)
            S[h][hi * 4 + r][cf * 16 + l15] = acc[r];
    }
    __syncthreads();

    {
        float mx = fmaxf(fmaxf(l0, l1), fmaxf(l2, l3));
        float s0 = __expf(l0 - mx), s1 = __expf(l1 - mx), s2 = __expf(l2 - mx), s3 = __expf(l3 - mx);
        float inv = 1.0f / (s0 + s1 + s2 + s3);
        float pi0 = s0 * inv + 1e-8f, pi1 = s1 * inv + 1e-8f;
        float pi2 = s2 * inv + 1e-8f, pi3 = s3 * inv + 1e-8f;

        const int tq = ttid >> 3;    // query row 0..15
        const int g  = ttid & 7;
        const int tg = t0 + tq;
        float att[8];
        #pragma unroll
        for (int u = 0; u < 8; ++u) {
            int o = g + 8 * u;
            int k = tg + o;
            if (k < T_SEQ) {
                int r0 = tq + o + 12;
                float z = pi0 * __expf(S[h][tq][r0])     + pi1 * __expf(S[h][tq][r0 - 4])
                        + pi2 * __expf(S[h][tq][r0 - 8]) + pi3 * __expf(S[h][tq][r0 - 12]);
                att[u] = __logf(z) - slope * (float)o;
            } else att[u] = -1e30f;
        }
        float m = att[0];
        #pragma unroll
        for (int u = 1; u < 8; ++u) m = fmaxf(m, att[u]);
        m = fmaxf(m, __shfl_xor(m, 1));
        m = fmaxf(m, __shfl_xor(m, 2));
        m = fmaxf(m, __shfl_xor(m, 4));
        float Zs = 0.0f;
        #pragma unroll
        for (int u = 0; u < 8; ++u) { att[u] = __expf(att[u] - m); Zs += att[u]; }
        Zs += __shfl_xor(Zs, 1);
        Zs += __shfl_xor(Zs, 2);
        Zs += __shfl_xor(Zs, 4);
        float rz = 1.0f / Zs;

        #pragma unroll
        for (int u = 0; u < 8; ++u) S[h][tq][tq + g + 8 * u + 12] = att[u] * rz;
        for (int i = g; i < 24; i += 8) {
            int slot = tq + (i < 12 ? i : i + 64);
            S[h][tq][slot] = 0.0f;
        }
        for (int rj = g; rj < 96; rj += 8) {
            float val = 0.0f;
            if (rj >= tq && rj <= tq + 75)
                val = S[h][tq][rj] + S[h][tq][rj + 4] + S[h][tq][rj + 8] + S[h][tq][rj + 12];
            S[h][tq][rj] = val;
        }
    }
    __syncthreads();

    {
        s16x8 ap[3];
        #pragma unroll
        for (int kt = 0; kt < 3; ++kt) {
            const float* sp = &S[h][l15][kt * 32 + hi * 8];
            ap[kt] = pack8(*(const float4*)sp, *(const float4*)(sp + 4));
        }
        #pragma unroll
        for (int i = 0; i < 2; ++i) {
            int c = wl * 2 + i;
            f32x4v acc = {};
            #pragma unroll
            for (int kt = 0; kt < 3; ++kt)
                acc = __builtin_amdgcn_mfma_f32_16x16x32_bf16(ap[kt], bvv[i][kt], acc, 0, 0, 0);
            #pragma unroll
            for (int r = 0; r < 4; ++r)
                ctxs[hi * 4 + r][h * 64 + c * 16 + l15] = f2bf(acc[r]);
        }
    }
    __syncthreads();

    {
        const int w8 = tid >> 6;
        s16x8 ao[8];
        #pragma unroll
        for (int kt = 0; kt < 8; ++kt)
            ao[kt] = *(const s16x8*)&ctxs[l15][kt * 32 + hi * 8];
        #pragma unroll
        for (int i = 0; i < 2; ++i) {
            int col = (w8 * 2 + i) * 16 + l15;
            const unsigned short* wrow = wob + (size_t)col * D_MODEL;
            f32x4v acc = {};
            #pragma unroll
            for (int kt = 0; kt < 8; ++kt)
                acc = __builtin_amdgcn_mfma_f32_16x16x32_bf16(
                    ao[kt], *(const s16x8*)(wrow + kt * 32 + hi * 8), acc, 0, 0, 0);
            float bs = bo[col];
            #pragma unroll
            for (int r = 0; r < 4; ++r)
                out[(size_t)(b * T_SEQ + t0 + hi * 4 + r) * D_MODEL + col] = acc[r] + bs;
        }
    }
}

extern "C" void kernel_launch(void* const* d_in, const int* in_sizes, int n_in,
                              void* d_out, int out_size, void* d_ws, size_t ws_size,
                              hipStream_t stream) {
    const float* x  = (const float*)d_in[0];
    const float* Wq = (const float*)d_in[1];
    const float* bq = (const float*)d_in[2];
    const float* Wk = (const float*)d_in[3];
    const float* bk = (const float*)d_in[4];
    const float* Wv = (const float*)d_in[5];
    const float* bv = (const float*)d_in[6];
    const float* Wo = (const float*)d_in[7];
    const float* bo = (const float*)d_in[8];
    const float* shift_logits = (const float*)d_in[9];
    const float* alibi_slope  = (const float*)d_in[10];
    float* out = (float*)d_out;

    char* ws = (char*)d_ws;
    unsigned short* qb  = (unsigned short*)(ws);                 // 2 MB
    unsigned short* kb  = (unsigned short*)(ws + (2u << 20));    // 2 MB
    unsigned short* vbT = (unsigned short*)(ws + (4u << 20));    // 2.25 MB
    unsigned short* wb  = (unsigned short*)(ws + (7u << 20));    // 512 KB (q,k,v,o bf16)
    unsigned short* xb  = (unsigned short*)(ws + (8u << 20));    // 2 MB

    cvt<<<dim3(640), dim3(256), 0, stream>>>(x, Wq, Wk, Wv, Wo, xb, wb);
    qkv_prep<<<dim3(64, 12), dim3(256), 0, stream>>>(
        xb, wb, bq, bk, bv, qb, kb, vbT);
    attn_o<<<dim3(256), dim3(512), 0, stream>>>(
        qb, kb, vbT, wb + 3 * (D_MODEL * D_MODEL), shift_logits, alibi_slope, bo, out);
}

// Round 16
// 29.885 us; speedup vs baseline: 1.0518x; 1.0518x over previous
//
#include <hip/hip_runtime.h>
#include <hip/hip_bf16.h>

#define T_SEQ 1024
#define D_MODEL 256
#define VBT_W 1152   // 12 front guard + 1024 + 116 back guard

typedef __attribute__((ext_vector_type(8))) short s16x8;
typedef __attribute__((ext_vector_type(4))) float f32x4v;

__device__ __forceinline__ unsigned short f2bf(float x) {
    union { float f; unsigned int u; } v; v.f = x;
    unsigned int r = v.u + 0x7FFFu + ((v.u >> 16) & 1u);
    return (unsigned short)(r >> 16);
}

__device__ __forceinline__ s16x8 pack8(float4 a, float4 b) {
    union { s16x8 v; unsigned int u[4]; } r;
    union { __hip_bfloat162 h; unsigned int u; } t;
    t.h = __float22bfloat162_rn(make_float2(a.x, a.y)); r.u[0] = t.u;
    t.h = __float22bfloat162_rn(make_float2(a.z, a.w)); r.u[1] = t.u;
    t.h = __float22bfloat162_rn(make_float2(b.x, b.y)); r.u[2] = t.u;
    t.h = __float22bfloat162_rn(make_float2(b.z, b.w)); r.u[3] = t.u;
    return r.v;
}

// ---- QKV GEMM + V-transpose + Wo cvt + guard zeroing ----
// bx-fast grid: output row-stripe r/64 is written by the block on XCD (r/64)%8.
__global__ __launch_bounds__(256) void qkv_prep(
    const float* __restrict__ x,
    const float* __restrict__ Wq, const float* __restrict__ bq,
    const float* __restrict__ Wk, const float* __restrict__ bk,
    const float* __restrict__ Wv, const float* __restrict__ bv,
    const float* __restrict__ Wo,
    unsigned short* __restrict__ qb, unsigned short* __restrict__ kb,
    unsigned short* __restrict__ vbT, unsigned short* __restrict__ wob)
{
    __shared__ unsigned short Bl[64][264];

    const int tid  = threadIdx.x;
    const int lane = tid & 63;
    const int w    = tid >> 6;
    const int l15  = lane & 15, hi = lane >> 4;
    const int row0 = blockIdx.x * 64;
    const int mat  = blockIdx.y >> 2;
    const int col0 = (blockIdx.y & 3) * 64;
    const int fid  = blockIdx.y * 64 + blockIdx.x;

    const float* W    = (mat == 0) ? Wq : (mat == 1) ? Wk : Wv;
    const float* bias = (mat == 0) ? bq : (mat == 1) ? bk : bv;

    const int arow = row0 + w * 16 + l15;
    const float* Ap = x + (size_t)arow * D_MODEL;
    float4 a4[16];
    #pragma unroll
    for (int kt = 0; kt < 8; ++kt) {
        a4[2 * kt]     = *(const float4*)(Ap + kt * 32 + hi * 8);
        a4[2 * kt + 1] = *(const float4*)(Ap + kt * 32 + hi * 8 + 4);
    }

    for (int i = tid; i < 2048; i += 256) {
        int r = i >> 5, c8 = i & 31;
        const float* p = W + (size_t)(col0 + r) * D_MODEL + c8 * 8;
        *(s16x8*)&Bl[r][c8 * 8] = pack8(*(const float4*)p, *(const float4*)(p + 4));
    }
    __syncthreads();

    f32x4v acc[4] = {};
    #pragma unroll
    for (int kt = 0; kt < 8; ++kt) {
        int koff = kt * 32 + hi * 8;
        s16x8 a = pack8(a4[2 * kt], a4[2 * kt + 1]);
        #pragma unroll
        for (int c = 0; c < 4; ++c)
            acc[c] = __builtin_amdgcn_mfma_f32_16x16x32_bf16(a, *(const s16x8*)&Bl[c * 16 + l15][koff], acc[c], 0, 0, 0);
    }
    if (mat == 2) {
        int bq4 = row0 >> 10;
        int j0  = (row0 & 1023) + w * 16 + hi * 4;
        #pragma unroll
        for (int c = 0; c < 4; ++c) {
            int col = col0 + c * 16 + l15;
            int hh = col >> 6, dh = col & 63;
            float bs = bias[col];
            union { ushort4 u4; unsigned short s[4]; } st;
            #pragma unroll
            for (int r = 0; r < 4; ++r) st.s[r] = f2bf(acc[c][r] + bs);
            *(ushort4*)(vbT + (size_t)((bq4 * 4 + hh) * 64 + dh) * VBT_W + 12 + j0) = st.u4;
        }
    } else {
        unsigned short* o = (mat == 0) ? qb : kb;
        float sc = (mat == 0) ? 0.125f : 1.0f;
        #pragma unroll
        for (int c = 0; c < 4; ++c) {
            int col = col0 + c * 16 + l15;
            float bs = bias[col];
            #pragma unroll
            for (int r = 0; r < 4; ++r) {
                int row = row0 + w * 16 + hi * 4 + r;
                o[(size_t)row * D_MODEL + col] = f2bf((acc[c][r] + bs) * sc);
            }
        }
    }

    int gid = fid * 256 + tid;
    if (gid < 1024 * 128) {
        int row = gid >> 7, g = gid & 127;
        int colg = (g < 12) ? g : (1024 + g);
        vbT[(size_t)row * VBT_W + colg] = 0;
    }
    if (gid < 8192) {
        const float* p = Wo + gid * 8;
        *(s16x8*)(wob + gid * 8) = pack8(*(const float4*)p, *(const float4*)(p + 4));
    }
}

// ---- attention + O projection; XCD-aligned decode: bid%8 == (t0/64)%8 ----
__global__ __launch_bounds__(512) void attn_o(
    const unsigned short* __restrict__ qb, const unsigned short* __restrict__ kb,
    const unsigned short* __restrict__ vbT, const unsigned short* __restrict__ wob,
    const float* __restrict__ shift_logits, const float* __restrict__ alibi_slope,
    const float* __restrict__ bo, float* __restrict__ out)
{
    __shared__ float S[4][16][104];          // 26624 B
    __shared__ unsigned short ctxs[16][264]; //  8448 B

    const int tid  = threadIdx.x;
    const int lane = tid & 63;
    const int l15  = lane & 15, hi = lane >> 4;
    const int h    = tid >> 7;        // head team
    const int ttid = tid & 127;
    const int wl   = (tid >> 6) & 1;  // wave within team

    // XCD-aligned decode (bijective over 256 blocks):
    const int bid = blockIdx.x;
    const int x7  = bid & 7;          // XCD
    const int i5  = bid >> 3;         // [0,32)
    const int s_  = x7 + 8 * (i5 & 1);        // 64-row stripe [0,16)
    const int tl  = (i5 >> 1) & 3;
    const int b   = i5 >> 3;                  // batch [0,4)
    const int t0  = (s_ * 4 + tl) * 16;
    const int jbase = t0 - 12;

    const unsigned short* qrow = qb + (size_t)(b * T_SEQ + t0 + l15) * D_MODEL + h * 64;
    s16x8 aq0 = *(const s16x8*)(qrow + hi * 8);
    s16x8 aq1 = *(const s16x8*)(qrow + 32 + hi * 8);

    s16x8 bk0[3], bk1[3];
    #pragma unroll
    for (int i = 0; i < 3; ++i) {
        int cf = wl + 2 * i;
        int j = jbase + cf * 16 + l15;
        s16x8 z = {0,0,0,0,0,0,0,0};
        bk0[i] = z; bk1[i] = z;
        if (j >= 0 && j < T_SEQ) {
            const unsigned short* kr = kb + (size_t)(b * T_SEQ + j) * D_MODEL + h * 64;
            bk0[i] = *(const s16x8*)(kr + hi * 8);
            bk1[i] = *(const s16x8*)(kr + 32 + hi * 8);
        }
    }
    s16x8 bvv[2][3];
    #pragma unroll
    for (int i = 0; i < 2; ++i) {
        int c = wl * 2 + i;
        const unsigned short* vrow =
            vbT + (size_t)((b * 4 + h) * 64 + c * 16 + l15) * VBT_W + t0;
        #pragma unroll
        for (int kt = 0; kt < 3; ++kt)
            bvv[i][kt] = *(const s16x8*)(vrow + kt * 32 + hi * 8);
    }
    float l0 = shift_logits[h * 4 + 0], l1 = shift_logits[h * 4 + 1];
    float l2 = shift_logits[h * 4 + 2], l3 = shift_logits[h * 4 + 3];
    float slope = alibi_slope[h];

    #pragma unroll
    for (int i = 0; i < 3; ++i) {
        int cf = wl + 2 * i;
        f32x4v acc = {};
        acc = __builtin_amdgcn_mfma_f32_16x16x32_bf16(aq0, bk0[i], acc, 0, 0, 0);
        acc = __builtin_amdgcn_mfma_f32_16x16x32_bf16(aq1, bk1[i], acc, 0, 0, 0);
        #pragma unroll
        for (int r = 0; r < 4; ++r)
            S[h][hi * 4 + r][cf * 16 + l15] = acc[r];
    }

    const int w8 = tid >> 6;
    s16x8 bw[2][8];
    #pragma unroll
    for (int i = 0; i < 2; ++i) {
        const unsigned short* wrow = wob + (size_t)((w8 * 2 + i) * 16 + l15) * D_MODEL;
        #pragma unroll
        for (int kt = 0; kt < 8; ++kt)
            bw[i][kt] = *(const s16x8*)(wrow + kt * 32 + hi * 8);
    }
    __syncthreads();

    {
        float mx = fmaxf(fmaxf(l0, l1), fmaxf(l2, l3));
        float s0 = __expf(l0 - mx), s1 = __expf(l1 - mx), s2 = __expf(l2 - mx), s3 = __expf(l3 - mx);
        float inv = 1.0f / (s0 + s1 + s2 + s3);
        float pi0 = s0 * inv + 1e-8f, pi1 = s1 * inv + 1e-8f;
        float pi2 = s2 * inv + 1e-8f, pi3 = s3 * inv + 1e-8f;

        const int tq = ttid >> 3;    // query row 0..15
        const int g  = ttid & 7;
        const int tg = t0 + tq;
        float att[8];
        #pragma unroll
        for (int u = 0; u < 8; ++u) {
            int o = g + 8 * u;
            int k = tg + o;
            if (k < T_SEQ) {
                int r0 = tq + o + 12;
                float z = pi0 * __expf(S[h][tq][r0])     + pi1 * __expf(S[h][tq][r0 - 4])
                        + pi2 * __expf(S[h][tq][r0 - 8]) + pi3 * __expf(S[h][tq][r0 - 12]);
                att[u] = __logf(z) - slope * (float)o;
            } else att[u] = -1e30f;
        }
        float m = att[0];
        #pragma unroll
        for (int u = 1; u < 8; ++u) m = fmaxf(m, att[u]);
        m = fmaxf(m, __shfl_xor(m, 1));
        m = fmaxf(m, __shfl_xor(m, 2));
        m = fmaxf(m, __shfl_xor(m, 4));
        float Zs = 0.0f;
        #pragma unroll
        for (int u = 0; u < 8; ++u) { att[u] = __expf(att[u] - m); Zs += att[u]; }
        Zs += __shfl_xor(Zs, 1);
        Zs += __shfl_xor(Zs, 2);
        Zs += __shfl_xor(Zs, 4);
        float rz = 1.0f / Zs;

        #pragma unroll
        for (int u = 0; u < 8; ++u) S[h][tq][tq + g + 8 * u + 12] = att[u] * rz;
        for (int i = g; i < 24; i += 8) {
            int slot = tq + (i < 12 ? i : i + 64);
            S[h][tq][slot] = 0.0f;
        }
        for (int rj = g; rj < 96; rj += 8) {
            float val = 0.0f;
            if (rj >= tq && rj <= tq + 75)
                val = S[h][tq][rj] + S[h][tq][rj + 4] + S[h][tq][rj + 8] + S[h][tq][rj + 12];
            S[h][tq][rj] = val;
        }
    }
    __syncthreads();

    {
        s16x8 ap[3];
        #pragma unroll
        for (int kt = 0; kt < 3; ++kt) {
            const float* sp = &S[h][l15][kt * 32 + hi * 8];
            ap[kt] = pack8(*(const float4*)sp, *(const float4*)(sp + 4));
        }
        #pragma unroll
        for (int i = 0; i < 2; ++i) {
            int c = wl * 2 + i;
            f32x4v acc = {};
            #pragma unroll
            for (int kt = 0; kt < 3; ++kt)
                acc = __builtin_amdgcn_mfma_f32_16x16x32_bf16(ap[kt], bvv[i][kt], acc, 0, 0, 0);
            #pragma unroll
            for (int r = 0; r < 4; ++r)
                ctxs[hi * 4 + r][h * 64 + c * 16 + l15] = f2bf(acc[r]);
        }
    }
    __syncthreads();

    {
        s16x8 ao[8];
        #pragma unroll
        for (int kt = 0; kt < 8; ++kt)
            ao[kt] = *(const s16x8*)&ctxs[l15][kt * 32 + hi * 8];
        #pragma unroll
        for (int i = 0; i < 2; ++i) {
            int col = (w8 * 2 + i) * 16 + l15;
            f32x4v acc = {};
            #pragma unroll
            for (int kt = 0; kt < 8; ++kt)
                acc = __builtin_amdgcn_mfma_f32_16x16x32_bf16(ao[kt], bw[i][kt], acc, 0, 0, 0);
            float bs = bo[col];
            #pragma unroll
            for (int r = 0; r < 4; ++r)
                out[(size_t)(b * T_SEQ + t0 + hi * 4 + r) * D_MODEL + col] = acc[r] + bs;
        }
    }
}

extern "C" void kernel_launch(void* const* d_in, const int* in_sizes, int n_in,
                              void* d_out, int out_size, void* d_ws, size_t ws_size,
                              hipStream_t stream) {
    const float* x  = (const float*)d_in[0];
    const float* Wq = (const float*)d_in[1];
    const float* bq = (const float*)d_in[2];
    const float* Wk = (const float*)d_in[3];
    const float* bk = (const float*)d_in[4];
    const float* Wv = (const float*)d_in[5];
    const float* bv = (const float*)d_in[6];
    const float* Wo = (const float*)d_in[7];
    const float* bo = (const float*)d_in[8];
    const float* shift_logits = (const float*)d_in[9];
    const float* alibi_slope  = (const float*)d_in[10];
    float* out = (float*)d_out;

    char* ws = (char*)d_ws;
    unsigned short* qb  = (unsigned short*)(ws);                 // 2 MB
    unsigned short* kb  = (unsigned short*)(ws + (2u << 20));    // 2 MB
    unsigned short* vbT = (unsigned short*)(ws + (4u << 20));    // 2.25 MB
    unsigned short* wob = (unsigned short*)(ws + (7u << 20));    // 128 KB

    qkv_prep<<<dim3(64, 12), dim3(256), 0, stream>>>(
        x, Wq, bq, Wk, bk, Wv, bv, Wo, qb, kb, vbT, wob);
    attn_o<<<dim3(256), dim3(512), 0, stream>>>(
        qb, kb, vbT, wob, shift_logits, alibi_slope, bo, out);
}